// Round 18
// baseline (211.431 us; speedup 1.0000x reference)
//
#include <hip/hip_runtime.h>

// GCN 2-layer. R18: break gemm1's dinv dependency (gemm1 emits UNSCALED h1u; gather64
// applies dinv[src] per edge) and overlap gemm1 with the CSR build via blockIdx-
// partitioned fused dispatches: fusedA = binfill + gemm1a, fusedB = bucket2csr + gemm1b.

#define NBKT(n) (((n) + 127) >> 7)

__device__ inline float bf2f(unsigned short u) {
    union { unsigned int i; float f; } v;
    v.i = ((unsigned int)u) << 16;
    return v.f;
}
__device__ inline unsigned short f2bf(float f) {
    union { float f; unsigned int i; } v;
    v.f = f;
    unsigned int u = v.i;
    return (unsigned short)((u + 0x7fff + ((u >> 16) & 1)) >> 16);  // RTN-even
}

// ---------------- bucket histogram (R13 proven) ----------------
#define BH_CHUNK 4096
__global__ void __launch_bounds__(256) bhist_kernel(
        const int* __restrict__ dst, int E, int nbk, int* __restrict__ bcnt) {
    __shared__ int cnt[NBKT(100000)];
    const int t = threadIdx.x;
    const int beg = blockIdx.x * BH_CHUNK;
    const int end = min(E, beg + BH_CHUNK);
    for (int b = t; b < nbk; b += 256) cnt[b] = 0;
    __syncthreads();
    for (int i = beg + t; i < end; i += 256) atomicAdd(&cnt[dst[i] >> 7], 1);
    __syncthreads();
    for (int b = t; b < nbk; b += 256) {
        int c = cnt[b];
        if (c) atomicAdd(&bcnt[b], c);
    }
}

// ---------------- bucket offsets (R13 proven) ----------------
__global__ void bscan_kernel(const int* __restrict__ bcnt, int nbk, int E,
                             int* __restrict__ boffs, int* __restrict__ gcursor) {
    __shared__ int s[1024];
    const int t = threadIdx.x;
    int v = (t < nbk) ? bcnt[t] : 0;
    s[t] = v;
    __syncthreads();
    for (int off = 1; off < 1024; off <<= 1) {
        int x = (t >= off) ? s[t - off] : 0;
        __syncthreads();
        s[t] += x;
        __syncthreads();
    }
    if (t < nbk) {
        int excl = s[t] - v;
        boffs[t] = excl;
        gcursor[t] = excl;
    }
    if (t == 0) boffs[nbk] = E;
}

// ---------------- gemm1 body (K=128, C=64, BR=64; fp32 in, bf16 out, NO dinv) --------
#define FMA4(ACC, AV, WV) \
    ACC.x += (AV) * (WV).x; ACC.y += (AV) * (WV).y; ACC.z += (AV) * (WV).z; ACC.w += (AV) * (WV).w;

__device__ __forceinline__ void gemm1_body(
        const float* __restrict__ A, const float* __restrict__ W,
        unsigned short* __restrict__ out, int N, int row0,
        float* Wl, float* Al) {
    constexpr int K = 128, C = 64, F4R = 32, CG = 16;
    const int t = threadIdx.x;
    for (int i = t; i < K * C / 4; i += 256) ((float4*)Wl)[i] = ((const float4*)W)[i];
    for (int i = t; i < 64 * F4R; i += 256) {
        int r = i / F4R, k4 = i % F4R;
        float4 v = make_float4(0.f, 0.f, 0.f, 0.f);
        if (row0 + r < N) v = ((const float4*)A)[(size_t)(row0 + r) * F4R + k4];
        *(float4*)(Al + r * K + k4 * 4) = v;
    }
    __syncthreads();

    const int c0 = (t % CG) * 4;
    const int r0 = (t / CG) * 4;
    const float* Ab = Al + r0 * K;
    float4 acc0 = {0, 0, 0, 0}, acc1 = {0, 0, 0, 0}, acc2 = {0, 0, 0, 0}, acc3 = {0, 0, 0, 0};

#pragma unroll 2
    for (int k4 = 0; k4 < K / 4; ++k4) {
        float4 a0 = *(const float4*)(Ab + 0 * K + k4 * 4);
        float4 a1 = *(const float4*)(Ab + 1 * K + k4 * 4);
        float4 a2 = *(const float4*)(Ab + 2 * K + k4 * 4);
        float4 a3 = *(const float4*)(Ab + 3 * K + k4 * 4);
        float4 w0 = *(const float4*)(Wl + (k4 * 4 + 0) * C + c0);
        float4 w1 = *(const float4*)(Wl + (k4 * 4 + 1) * C + c0);
        float4 w2 = *(const float4*)(Wl + (k4 * 4 + 2) * C + c0);
        float4 w3 = *(const float4*)(Wl + (k4 * 4 + 3) * C + c0);
        FMA4(acc0, a0.x, w0) FMA4(acc1, a1.x, w0) FMA4(acc2, a2.x, w0) FMA4(acc3, a3.x, w0)
        FMA4(acc0, a0.y, w1) FMA4(acc1, a1.y, w1) FMA4(acc2, a2.y, w1) FMA4(acc3, a3.y, w1)
        FMA4(acc0, a0.z, w2) FMA4(acc1, a1.z, w2) FMA4(acc2, a2.z, w2) FMA4(acc3, a3.z, w2)
        FMA4(acc0, a0.w, w3) FMA4(acc1, a1.w, w3) FMA4(acc2, a2.w, w3) FMA4(acc3, a3.w, w3)
    }

    const int row = row0 + r0;
#pragma unroll
    for (int i = 0; i < 4; ++i) {
        int rr = row + i;
        if (rr < N) {
            float4 fr = (i == 0) ? acc0 : (i == 1) ? acc1 : (i == 2) ? acc2 : acc3;
            ushort4 o;
            o.x = f2bf(fr.x); o.y = f2bf(fr.y); o.z = f2bf(fr.z); o.w = f2bf(fr.w);
            *(ushort4*)(out + (size_t)rr * C + c0) = o;
        }
    }
}

// ---------------- fused A: binfill (blocks < nBin) + gemm1a ----------------
#define BF_CHUNK 4096
__global__ void __launch_bounds__(256) fusedA_kernel(
        const int* __restrict__ src, const int* __restrict__ dst, int E, int nbk,
        int* __restrict__ gcursor, int* __restrict__ entries, int nBin,
        const float* __restrict__ x, const float* __restrict__ W1,
        unsigned short* __restrict__ h1u, int N) {
    __shared__ float smem[16384];  // 64KB: gemm Wl+Al, or binfill cnt/gbase/rank
    if ((int)blockIdx.x < nBin) {
        int* cnt = (int*)smem;
        int* gbase = cnt + NBKT(100000);
        int* rank = gbase + NBKT(100000);
        const int t = threadIdx.x;
        const int beg = blockIdx.x * BF_CHUNK;
        const int end = min(E, beg + BF_CHUNK);
        for (int b = t; b < nbk; b += 256) cnt[b] = 0;
        __syncthreads();
        for (int i = beg + t; i < end; i += 256) atomicAdd(&cnt[dst[i] >> 7], 1);
        __syncthreads();
        for (int b = t; b < nbk; b += 256) {
            int c = cnt[b];
            gbase[b] = c ? atomicAdd(&gcursor[b], c) : 0;
            rank[b] = 0;
        }
        __syncthreads();
        for (int i = beg + t; i < end; i += 256) {
            int d = dst[i];
            int b = d >> 7;
            int r = atomicAdd(&rank[b], 1);
            entries[gbase[b] + r] = (src[i] << 7) | (d & 127);
        }
    } else {
        int row0 = (blockIdx.x - nBin) * 64;  // rows [0, nGemmA*64)
        gemm1_body(x, W1, h1u, N, row0, smem, smem + 128 * 64);
    }
}

// ---------------- fused B: bucket2csr (blocks < nbk) + gemm1b ----------------
__global__ void __launch_bounds__(256) fusedB_kernel(
        const int* __restrict__ entries, const int* __restrict__ boffs, int nbk,
        int* __restrict__ offs, int* __restrict__ csr_src, float* __restrict__ dinv,
        int N, int E,
        const float* __restrict__ x, const float* __restrict__ W1,
        unsigned short* __restrict__ h1u, int rowBase) {
    __shared__ float smem[16384];  // 64KB
    if ((int)blockIdx.x < nbk) {
        int* cnt = (int*)smem;
        int* s = cnt + 128;
        int* rank = s + 128;
        const int t = threadIdx.x;
        const int b = blockIdx.x;
        const int beg = boffs[b];
        const int end = boffs[b + 1];
        if (t < 128) { cnt[t] = 0; rank[t] = 0; }
        __syncthreads();
        for (int i = beg + t; i < end; i += 256) atomicAdd(&cnt[entries[i] & 127], 1);
        __syncthreads();
        if (t < 128) s[t] = cnt[t];
        __syncthreads();
        for (int off = 1; off < 128; off <<= 1) {
            int x2 = 0;
            if (t < 128 && t >= off) x2 = s[t - off];
            __syncthreads();
            if (t < 128) s[t] += x2;
            __syncthreads();
        }
        const int node0 = b * 128;
        if (t < 128 && node0 + t < N) {
            offs[node0 + t] = beg + s[t] - cnt[t];
            dinv[node0 + t] = rsqrtf((float)cnt[t] + 1.0f);  // +1 = self-loop
        }
        if (b == 0 && t == 0) offs[N] = E;
        __syncthreads();
        for (int i = beg + t; i < end; i += 256) {
            int e = entries[i];
            int d = e & 127;
            int r = atomicAdd(&rank[d], 1);
            csr_src[beg + s[d] - cnt[d] + r] = (int)((unsigned)e >> 7);
        }
    } else {
        int row0 = rowBase + (blockIdx.x - nbk) * 64;
        gemm1_body(x, W1, h1u, N, row0, smem, smem + 128 * 64);
    }
}

// ---------------- gemm2 (templated, R6 proven): bf16 in, bf16 out, dinv scale --------
template <int K, int C, int BR>
__global__ void __launch_bounds__(256) gemm2_kernel(
        const unsigned short* __restrict__ A, const float* __restrict__ W,
        const float* __restrict__ dinv, unsigned short* __restrict__ out, int N) {
    constexpr int F4R = K / 4;
    constexpr int CG = C / 4;
    static_assert(256 / CG * 4 == BR, "geometry");
    __shared__ float Wl[K * C];
    __shared__ float Al[BR * K];

    const int t = threadIdx.x;
    for (int i = t; i < K * C / 4; i += 256) ((float4*)Wl)[i] = ((const float4*)W)[i];
    const int row0 = blockIdx.x * BR;
    for (int i = t; i < BR * F4R; i += 256) {
        int r = i / F4R, k4 = i % F4R;
        float4 v = make_float4(0.f, 0.f, 0.f, 0.f);
        if (row0 + r < N) {
            ushort4 u = ((const ushort4*)A)[(size_t)(row0 + r) * F4R + k4];
            v.x = bf2f(u.x); v.y = bf2f(u.y); v.z = bf2f(u.z); v.w = bf2f(u.w);
        }
        *(float4*)(Al + r * K + k4 * 4) = v;
    }
    __syncthreads();

    const int c0 = (t % CG) * 4;
    const int r0 = (t / CG) * 4;
    const float* Ab = Al + r0 * K;
    float4 acc0 = {0, 0, 0, 0}, acc1 = {0, 0, 0, 0}, acc2 = {0, 0, 0, 0}, acc3 = {0, 0, 0, 0};

#pragma unroll 2
    for (int k4 = 0; k4 < K / 4; ++k4) {
        float4 a0 = *(const float4*)(Ab + 0 * K + k4 * 4);
        float4 a1 = *(const float4*)(Ab + 1 * K + k4 * 4);
        float4 a2 = *(const float4*)(Ab + 2 * K + k4 * 4);
        float4 a3 = *(const float4*)(Ab + 3 * K + k4 * 4);
        float4 w0 = *(const float4*)(Wl + (k4 * 4 + 0) * C + c0);
        float4 w1 = *(const float4*)(Wl + (k4 * 4 + 1) * C + c0);
        float4 w2 = *(const float4*)(Wl + (k4 * 4 + 2) * C + c0);
        float4 w3 = *(const float4*)(Wl + (k4 * 4 + 3) * C + c0);
        FMA4(acc0, a0.x, w0) FMA4(acc1, a1.x, w0) FMA4(acc2, a2.x, w0) FMA4(acc3, a3.x, w0)
        FMA4(acc0, a0.y, w1) FMA4(acc1, a1.y, w1) FMA4(acc2, a2.y, w1) FMA4(acc3, a3.y, w1)
        FMA4(acc0, a0.z, w2) FMA4(acc1, a1.z, w2) FMA4(acc2, a2.z, w2) FMA4(acc3, a3.z, w2)
        FMA4(acc0, a0.w, w3) FMA4(acc1, a1.w, w3) FMA4(acc2, a2.w, w3) FMA4(acc3, a3.w, w3)
    }

    const int row = row0 + r0;
#pragma unroll
    for (int i = 0; i < 4; ++i) {
        int rr = row + i;
        if (rr < N) {
            float d = dinv[rr];
            float4 fr = (i == 0) ? acc0 : (i == 1) ? acc1 : (i == 2) ? acc2 : acc3;
            ushort4 o;
            o.x = f2bf(fr.x * d); o.y = f2bf(fr.y * d);
            o.z = f2bf(fr.z * d); o.w = f2bf(fr.w * d);
            *(ushort4*)(out + (size_t)rr * C + c0) = o;
        }
    }
}

// ---------------- gather C=64: one node/wave, 16 edges in flight, per-edge dinv[s] ---
#define G64_LOAD(SS) bf2f(hs[(size_t)(SS) * 64 + lane])
__global__ void __launch_bounds__(256) gather64_kernel(
        const unsigned short* __restrict__ hs, const float* __restrict__ dinv,
        const int* __restrict__ offs, const int* __restrict__ csr_src,
        const float* __restrict__ b, unsigned short* __restrict__ out, int N) {
    const int lane = threadIdx.x & 63;
    const int d = blockIdx.x * 4 + (threadIdx.x >> 6);  // wave-uniform
    if (d >= N) return;
    const int beg = offs[d];
    const int end = offs[d + 1];
    const float dv = dinv[d];
    float acc0 = G64_LOAD(d) * dv;  // self-loop: h1u[d]*dinv[d]
    float acc1 = 0.f, acc2 = 0.f, acc3 = 0.f;
    int j = beg;
    for (; j + 15 < end; j += 16) {
        int s0 = csr_src[j + 0], s1 = csr_src[j + 1], s2 = csr_src[j + 2], s3 = csr_src[j + 3];
        int s4 = csr_src[j + 4], s5 = csr_src[j + 5], s6 = csr_src[j + 6], s7 = csr_src[j + 7];
        int s8 = csr_src[j + 8], s9 = csr_src[j + 9], sa = csr_src[j + 10], sb = csr_src[j + 11];
        int sc = csr_src[j + 12], sd = csr_src[j + 13], se = csr_src[j + 14], sf = csr_src[j + 15];
        float w0 = dinv[s0], w1 = dinv[s1], w2 = dinv[s2], w3 = dinv[s3];
        float w4 = dinv[s4], w5 = dinv[s5], w6 = dinv[s6], w7 = dinv[s7];
        float w8 = dinv[s8], w9 = dinv[s9], wa = dinv[sa], wb = dinv[sb];
        float wc = dinv[sc], wd = dinv[sd], we = dinv[se], wf = dinv[sf];
        float v0 = G64_LOAD(s0), v1 = G64_LOAD(s1), v2 = G64_LOAD(s2), v3 = G64_LOAD(s3);
        float v4 = G64_LOAD(s4), v5 = G64_LOAD(s5), v6 = G64_LOAD(s6), v7 = G64_LOAD(s7);
        float v8 = G64_LOAD(s8), v9 = G64_LOAD(s9), va = G64_LOAD(sa), vb = G64_LOAD(sb);
        float vc = G64_LOAD(sc), vd = G64_LOAD(sd), ve = G64_LOAD(se), vf = G64_LOAD(sf);
        acc0 += v0 * w0; acc1 += v1 * w1; acc2 += v2 * w2; acc3 += v3 * w3;
        acc0 += v4 * w4; acc1 += v5 * w5; acc2 += v6 * w6; acc3 += v7 * w7;
        acc0 += v8 * w8; acc1 += v9 * w9; acc2 += va * wa; acc3 += vb * wb;
        acc0 += vc * wc; acc1 += vd * wd; acc2 += ve * we; acc3 += vf * wf;
    }
    if (j + 7 < end) {
        int s0 = csr_src[j + 0], s1 = csr_src[j + 1], s2 = csr_src[j + 2], s3 = csr_src[j + 3];
        int s4 = csr_src[j + 4], s5 = csr_src[j + 5], s6 = csr_src[j + 6], s7 = csr_src[j + 7];
        float w0 = dinv[s0], w1 = dinv[s1], w2 = dinv[s2], w3 = dinv[s3];
        float w4 = dinv[s4], w5 = dinv[s5], w6 = dinv[s6], w7 = dinv[s7];
        float v0 = G64_LOAD(s0), v1 = G64_LOAD(s1), v2 = G64_LOAD(s2), v3 = G64_LOAD(s3);
        float v4 = G64_LOAD(s4), v5 = G64_LOAD(s5), v6 = G64_LOAD(s6), v7 = G64_LOAD(s7);
        acc0 += v0 * w0; acc1 += v1 * w1; acc2 += v2 * w2; acc3 += v3 * w3;
        acc0 += v4 * w4; acc1 += v5 * w5; acc2 += v6 * w6; acc3 += v7 * w7;
        j += 8;
    }
    if (j + 3 < end) {
        int s0 = csr_src[j + 0], s1 = csr_src[j + 1], s2 = csr_src[j + 2], s3 = csr_src[j + 3];
        float w0 = dinv[s0], w1 = dinv[s1], w2 = dinv[s2], w3 = dinv[s3];
        acc0 += G64_LOAD(s0) * w0; acc1 += G64_LOAD(s1) * w1;
        acc2 += G64_LOAD(s2) * w2; acc3 += G64_LOAD(s3) * w3;
        j += 4;
    }
    for (; j < end; ++j) {
        int s = csr_src[j];
        acc0 += G64_LOAD(s) * dinv[s];
    }
    float r = ((acc0 + acc1) + (acc2 + acc3)) * dv + b[lane];
    r = fmaxf(r, 0.f);  // relu (layer 1)
    out[(size_t)d * 64 + lane] = f2bf(r);
}

// ---------------- gather C=32 (R14 proven): 2 nodes/wave, 16 edges, pre-scaled table -
#define G32_LOAD(SS) bf2f(hs[(size_t)(SS) * 32 + lane])
__global__ void __launch_bounds__(256) gather32_kernel(
        const unsigned short* __restrict__ hs, const float* __restrict__ dinv,
        const int* __restrict__ offs, const int* __restrict__ csr_src,
        const float* __restrict__ b, float* __restrict__ out, int N) {
    const int lane = threadIdx.x & 31;
    const int d = blockIdx.x * 8 + (threadIdx.x >> 5);
    if (d >= N) return;
    const int beg = offs[d];
    const int end = offs[d + 1];
    float acc0 = G32_LOAD(d);  // self-loop (pre-scaled table)
    float acc1 = 0.f, acc2 = 0.f, acc3 = 0.f;
    int j = beg;
    for (; j + 15 < end; j += 16) {
        int s0 = csr_src[j + 0], s1 = csr_src[j + 1], s2 = csr_src[j + 2], s3 = csr_src[j + 3];
        int s4 = csr_src[j + 4], s5 = csr_src[j + 5], s6 = csr_src[j + 6], s7 = csr_src[j + 7];
        int s8 = csr_src[j + 8], s9 = csr_src[j + 9], sa = csr_src[j + 10], sb = csr_src[j + 11];
        int sc = csr_src[j + 12], sd = csr_src[j + 13], se = csr_src[j + 14], sf = csr_src[j + 15];
        float v0 = G32_LOAD(s0), v1 = G32_LOAD(s1), v2 = G32_LOAD(s2), v3 = G32_LOAD(s3);
        float v4 = G32_LOAD(s4), v5 = G32_LOAD(s5), v6 = G32_LOAD(s6), v7 = G32_LOAD(s7);
        float v8 = G32_LOAD(s8), v9 = G32_LOAD(s9), va = G32_LOAD(sa), vb = G32_LOAD(sb);
        float vc = G32_LOAD(sc), vd = G32_LOAD(sd), ve = G32_LOAD(se), vf = G32_LOAD(sf);
        acc0 += v0; acc1 += v1; acc2 += v2; acc3 += v3;
        acc0 += v4; acc1 += v5; acc2 += v6; acc3 += v7;
        acc0 += v8; acc1 += v9; acc2 += va; acc3 += vb;
        acc0 += vc; acc1 += vd; acc2 += ve; acc3 += vf;
    }
    if (j + 7 < end) {
        int s0 = csr_src[j + 0], s1 = csr_src[j + 1], s2 = csr_src[j + 2], s3 = csr_src[j + 3];
        int s4 = csr_src[j + 4], s5 = csr_src[j + 5], s6 = csr_src[j + 6], s7 = csr_src[j + 7];
        float v0 = G32_LOAD(s0), v1 = G32_LOAD(s1), v2 = G32_LOAD(s2), v3 = G32_LOAD(s3);
        float v4 = G32_LOAD(s4), v5 = G32_LOAD(s5), v6 = G32_LOAD(s6), v7 = G32_LOAD(s7);
        acc0 += v0; acc1 += v1; acc2 += v2; acc3 += v3;
        acc0 += v4; acc1 += v5; acc2 += v6; acc3 += v7;
        j += 8;
    }
    if (j + 3 < end) {
        int s0 = csr_src[j + 0], s1 = csr_src[j + 1], s2 = csr_src[j + 2], s3 = csr_src[j + 3];
        acc0 += G32_LOAD(s0); acc1 += G32_LOAD(s1); acc2 += G32_LOAD(s2); acc3 += G32_LOAD(s3);
        j += 4;
    }
    for (; j < end; ++j) acc0 += G32_LOAD(csr_src[j]);
    float r = ((acc0 + acc1) + (acc2 + acc3)) * dinv[d] + b[lane];
    out[(size_t)d * 32 + lane] = r;
}

extern "C" void kernel_launch(void* const* d_in, const int* in_sizes, int n_in,
                              void* d_out, int out_size, void* d_ws, size_t ws_size,
                              hipStream_t stream) {
    const float* x = (const float*)d_in[0];
    const int* ei = (const int*)d_in[1];
    const float* W1 = (const float*)d_in[2];
    const float* b1 = (const float*)d_in[3];
    const float* W2 = (const float*)d_in[4];
    const float* b2 = (const float*)d_in[5];

    const int N = in_sizes[0] / 128;  // 100000
    const int E = in_sizes[1] / 2;    // 1600000
    const int* src = ei;
    const int* dst = ei + E;
    const int nbk = NBKT(N);          // 782

    // workspace layout (4-byte units unless noted)
    int* bcnt = (int*)d_ws;                            // nbk (pad 1024)
    int* boffs = bcnt + 1024;                          // nbk+1 (pad 1024)
    int* gcursor = boffs + 1024;                       // nbk (pad 1024)
    float* dinv = (float*)(gcursor + 1024);            // N
    int* offs = (int*)(dinv + ((N + 255) & ~255));     // N+1
    int* entries = offs + ((N + 1 + 255) & ~255);      // E
    int* csr_src = entries + ((E + 255) & ~255);       // E
    unsigned short* h1u = (unsigned short*)(csr_src + ((E + 255) & ~255));  // N*64 bf16
    unsigned short* h2b = h1u + (size_t)N * 64;        // N*64 bf16
    unsigned short* h3s = h1u;                         // reuse h1u region (N*32 bf16)
    float* out = (float*)d_out;

    const int nBin = (E + BF_CHUNK - 1) / BF_CHUNK;    // 391
    const int GB = (N + 63) / 64;                      // 1563 gemm1 tiles
    const int GA = GB / 2;                             // 781 in fusedA
    const int GBB = GB - GA;                           // 782 in fusedB
    const int rowBase = GA * 64;

    // 1) bucket histogram -> offsets
    hipMemsetAsync(bcnt, 0, 1024 * 4, stream);
    bhist_kernel<<<(E + BH_CHUNK - 1) / BH_CHUNK, 256, 0, stream>>>(dst, E, nbk, bcnt);
    bscan_kernel<<<1, 1024, 0, stream>>>(bcnt, nbk, E, boffs, gcursor);

    // 2) fusedA: binfill + gemm1 rows [0, rowBase)
    fusedA_kernel<<<nBin + GA, 256, 0, stream>>>(src, dst, E, nbk, gcursor, entries, nBin,
                                                 x, W1, h1u, N);

    // 3) fusedB: bucket2csr (emits offs, csr_src, dinv) + gemm1 rows [rowBase, N)
    fusedB_kernel<<<nbk + GBB, 256, 0, stream>>>(entries, boffs, nbk, offs, csr_src, dinv,
                                                 N, E, x, W1, h1u, rowBase);

    // 4) h2b = bf16(relu(dinv_d*(sum h1u[s]*dinv_s + h1u[d]*dinv_d) + b1))
    gather64_kernel<<<(N + 3) / 4, 256, 0, stream>>>(h1u, dinv, offs, csr_src, b1, h2b, N);

    // 5) h3s = bf16((h2b @ W2) * dinv)
    gemm2_kernel<64, 32, 128><<<(N + 127) / 128, 256, 0, stream>>>(h2b, W2, dinv, h3s, N);

    // 6) out = dinv*(gather h3s) + b2   (fp32)
    gather32_kernel<<<(N + 7) / 8, 256, 0, stream>>>(h3s, dinv, offs, csr_src, b2, out, N);
}

// Round 19
// 201.424 us; speedup vs baseline: 1.0497x; 1.0497x over previous
//
#include <hip/hip_runtime.h>

// GCN 2-layer. R19: keep R18's CSR/gemm1 overlap (fusedA/fusedB, unscaled h1u), but
// restore gather64's pre-scaled table via a cheap scale_h1 pass (h1u *= dinv, 25.6MB
// coalesced, ~5us). R18's per-edge dinv loads doubled gather64's VMEM ops (+17us).

#define NBKT(n) (((n) + 127) >> 7)

__device__ inline float bf2f(unsigned short u) {
    union { unsigned int i; float f; } v;
    v.i = ((unsigned int)u) << 16;
    return v.f;
}
__device__ inline unsigned short f2bf(float f) {
    union { float f; unsigned int i; } v;
    v.f = f;
    unsigned int u = v.i;
    return (unsigned short)((u + 0x7fff + ((u >> 16) & 1)) >> 16);  // RTN-even
}

// ---------------- bucket histogram (R13 proven) ----------------
#define BH_CHUNK 4096
__global__ void __launch_bounds__(256) bhist_kernel(
        const int* __restrict__ dst, int E, int nbk, int* __restrict__ bcnt) {
    __shared__ int cnt[NBKT(100000)];
    const int t = threadIdx.x;
    const int beg = blockIdx.x * BH_CHUNK;
    const int end = min(E, beg + BH_CHUNK);
    for (int b = t; b < nbk; b += 256) cnt[b] = 0;
    __syncthreads();
    for (int i = beg + t; i < end; i += 256) atomicAdd(&cnt[dst[i] >> 7], 1);
    __syncthreads();
    for (int b = t; b < nbk; b += 256) {
        int c = cnt[b];
        if (c) atomicAdd(&bcnt[b], c);
    }
}

// ---------------- bucket offsets (R13 proven) ----------------
__global__ void bscan_kernel(const int* __restrict__ bcnt, int nbk, int E,
                             int* __restrict__ boffs, int* __restrict__ gcursor) {
    __shared__ int s[1024];
    const int t = threadIdx.x;
    int v = (t < nbk) ? bcnt[t] : 0;
    s[t] = v;
    __syncthreads();
    for (int off = 1; off < 1024; off <<= 1) {
        int x = (t >= off) ? s[t - off] : 0;
        __syncthreads();
        s[t] += x;
        __syncthreads();
    }
    if (t < nbk) {
        int excl = s[t] - v;
        boffs[t] = excl;
        gcursor[t] = excl;
    }
    if (t == 0) boffs[nbk] = E;
}

// ---------------- gemm1 body (K=128, C=64, BR=64; fp32 in, bf16 out, NO dinv) --------
#define FMA4(ACC, AV, WV) \
    ACC.x += (AV) * (WV).x; ACC.y += (AV) * (WV).y; ACC.z += (AV) * (WV).z; ACC.w += (AV) * (WV).w;

__device__ __forceinline__ void gemm1_body(
        const float* __restrict__ A, const float* __restrict__ W,
        unsigned short* __restrict__ out, int N, int row0,
        float* Wl, float* Al) {
    constexpr int K = 128, C = 64, F4R = 32, CG = 16;
    const int t = threadIdx.x;
    for (int i = t; i < K * C / 4; i += 256) ((float4*)Wl)[i] = ((const float4*)W)[i];
    for (int i = t; i < 64 * F4R; i += 256) {
        int r = i / F4R, k4 = i % F4R;
        float4 v = make_float4(0.f, 0.f, 0.f, 0.f);
        if (row0 + r < N) v = ((const float4*)A)[(size_t)(row0 + r) * F4R + k4];
        *(float4*)(Al + r * K + k4 * 4) = v;
    }
    __syncthreads();

    const int c0 = (t % CG) * 4;
    const int r0 = (t / CG) * 4;
    const float* Ab = Al + r0 * K;
    float4 acc0 = {0, 0, 0, 0}, acc1 = {0, 0, 0, 0}, acc2 = {0, 0, 0, 0}, acc3 = {0, 0, 0, 0};

#pragma unroll 2
    for (int k4 = 0; k4 < K / 4; ++k4) {
        float4 a0 = *(const float4*)(Ab + 0 * K + k4 * 4);
        float4 a1 = *(const float4*)(Ab + 1 * K + k4 * 4);
        float4 a2 = *(const float4*)(Ab + 2 * K + k4 * 4);
        float4 a3 = *(const float4*)(Ab + 3 * K + k4 * 4);
        float4 w0 = *(const float4*)(Wl + (k4 * 4 + 0) * C + c0);
        float4 w1 = *(const float4*)(Wl + (k4 * 4 + 1) * C + c0);
        float4 w2 = *(const float4*)(Wl + (k4 * 4 + 2) * C + c0);
        float4 w3 = *(const float4*)(Wl + (k4 * 4 + 3) * C + c0);
        FMA4(acc0, a0.x, w0) FMA4(acc1, a1.x, w0) FMA4(acc2, a2.x, w0) FMA4(acc3, a3.x, w0)
        FMA4(acc0, a0.y, w1) FMA4(acc1, a1.y, w1) FMA4(acc2, a2.y, w1) FMA4(acc3, a3.y, w1)
        FMA4(acc0, a0.z, w2) FMA4(acc1, a1.z, w2) FMA4(acc2, a2.z, w2) FMA4(acc3, a3.z, w2)
        FMA4(acc0, a0.w, w3) FMA4(acc1, a1.w, w3) FMA4(acc2, a2.w, w3) FMA4(acc3, a3.w, w3)
    }

    const int row = row0 + r0;
#pragma unroll
    for (int i = 0; i < 4; ++i) {
        int rr = row + i;
        if (rr < N) {
            float4 fr = (i == 0) ? acc0 : (i == 1) ? acc1 : (i == 2) ? acc2 : acc3;
            ushort4 o;
            o.x = f2bf(fr.x); o.y = f2bf(fr.y); o.z = f2bf(fr.z); o.w = f2bf(fr.w);
            *(ushort4*)(out + (size_t)rr * C + c0) = o;
        }
    }
}

// ---------------- fused A: binfill (blocks < nBin) + gemm1a ----------------
#define BF_CHUNK 4096
__global__ void __launch_bounds__(256) fusedA_kernel(
        const int* __restrict__ src, const int* __restrict__ dst, int E, int nbk,
        int* __restrict__ gcursor, int* __restrict__ entries, int nBin,
        const float* __restrict__ x, const float* __restrict__ W1,
        unsigned short* __restrict__ h1u, int N) {
    __shared__ float smem[16384];  // 64KB
    if ((int)blockIdx.x < nBin) {
        int* cnt = (int*)smem;
        int* gbase = cnt + NBKT(100000);
        int* rank = gbase + NBKT(100000);
        const int t = threadIdx.x;
        const int beg = blockIdx.x * BF_CHUNK;
        const int end = min(E, beg + BF_CHUNK);
        for (int b = t; b < nbk; b += 256) cnt[b] = 0;
        __syncthreads();
        for (int i = beg + t; i < end; i += 256) atomicAdd(&cnt[dst[i] >> 7], 1);
        __syncthreads();
        for (int b = t; b < nbk; b += 256) {
            int c = cnt[b];
            gbase[b] = c ? atomicAdd(&gcursor[b], c) : 0;
            rank[b] = 0;
        }
        __syncthreads();
        for (int i = beg + t; i < end; i += 256) {
            int d = dst[i];
            int b = d >> 7;
            int r = atomicAdd(&rank[b], 1);
            entries[gbase[b] + r] = (src[i] << 7) | (d & 127);
        }
    } else {
        int row0 = (blockIdx.x - nBin) * 64;
        gemm1_body(x, W1, h1u, N, row0, smem, smem + 128 * 64);
    }
}

// ---------------- fused B: bucket2csr (blocks < nbk) + gemm1b ----------------
__global__ void __launch_bounds__(256) fusedB_kernel(
        const int* __restrict__ entries, const int* __restrict__ boffs, int nbk,
        int* __restrict__ offs, int* __restrict__ csr_src, float* __restrict__ dinv,
        int N, int E,
        const float* __restrict__ x, const float* __restrict__ W1,
        unsigned short* __restrict__ h1u, int rowBase) {
    __shared__ float smem[16384];  // 64KB
    if ((int)blockIdx.x < nbk) {
        int* cnt = (int*)smem;
        int* s = cnt + 128;
        int* rank = s + 128;
        const int t = threadIdx.x;
        const int b = blockIdx.x;
        const int beg = boffs[b];
        const int end = boffs[b + 1];
        if (t < 128) { cnt[t] = 0; rank[t] = 0; }
        __syncthreads();
        for (int i = beg + t; i < end; i += 256) atomicAdd(&cnt[entries[i] & 127], 1);
        __syncthreads();
        if (t < 128) s[t] = cnt[t];
        __syncthreads();
        for (int off = 1; off < 128; off <<= 1) {
            int x2 = 0;
            if (t < 128 && t >= off) x2 = s[t - off];
            __syncthreads();
            if (t < 128) s[t] += x2;
            __syncthreads();
        }
        const int node0 = b * 128;
        if (t < 128 && node0 + t < N) {
            offs[node0 + t] = beg + s[t] - cnt[t];
            dinv[node0 + t] = rsqrtf((float)cnt[t] + 1.0f);  // +1 = self-loop
        }
        if (b == 0 && t == 0) offs[N] = E;
        __syncthreads();
        for (int i = beg + t; i < end; i += 256) {
            int e = entries[i];
            int d = e & 127;
            int r = atomicAdd(&rank[d], 1);
            csr_src[beg + s[d] - cnt[d] + r] = (int)((unsigned)e >> 7);
        }
    } else {
        int row0 = rowBase + (blockIdx.x - nbk) * 64;
        gemm1_body(x, W1, h1u, N, row0, smem, smem + 128 * 64);
    }
}

// ---------------- scale_h1: h1u[row][*] *= dinv[row]  (bf16 in-place, coalesced) -----
__global__ void __launch_bounds__(256) scale_h1_kernel(
        unsigned short* __restrict__ h, const float* __restrict__ dinv, int N) {
    int idx = blockIdx.x * 256 + threadIdx.x;  // one thread per 8 bf16 (16B)
    if (idx >= N * 8) return;
    float d = dinv[idx >> 3];
    uint4* p = (uint4*)h + idx;
    uint4 v = *p;
#define SCH(U) { \
        float lo = bf2f((unsigned short)((U) & 0xffffu)) * d; \
        float hi = bf2f((unsigned short)((U) >> 16)) * d; \
        (U) = (unsigned)f2bf(lo) | ((unsigned)f2bf(hi) << 16); }
    SCH(v.x) SCH(v.y) SCH(v.z) SCH(v.w)
#undef SCH
    *p = v;
}

// ---------------- gemm2 (R6/R17 proven): bf16 in, bf16 out, dinv scale ----------------
template <int K, int C, int BR>
__global__ void __launch_bounds__(256) gemm2_kernel(
        const unsigned short* __restrict__ A, const float* __restrict__ W,
        const float* __restrict__ dinv, unsigned short* __restrict__ out, int N) {
    constexpr int F4R = K / 4;
    constexpr int CG = C / 4;
    static_assert(256 / CG * 4 == BR, "geometry");
    __shared__ float Wl[K * C];
    __shared__ float Al[BR * K];

    const int t = threadIdx.x;
    for (int i = t; i < K * C / 4; i += 256) ((float4*)Wl)[i] = ((const float4*)W)[i];
    const int row0 = blockIdx.x * BR;
    for (int i = t; i < BR * F4R; i += 256) {
        int r = i / F4R, k4 = i % F4R;
        float4 v = make_float4(0.f, 0.f, 0.f, 0.f);
        if (row0 + r < N) {
            ushort4 u = ((const ushort4*)A)[(size_t)(row0 + r) * F4R + k4];
            v.x = bf2f(u.x); v.y = bf2f(u.y); v.z = bf2f(u.z); v.w = bf2f(u.w);
        }
        *(float4*)(Al + r * K + k4 * 4) = v;
    }
    __syncthreads();

    const int c0 = (t % CG) * 4;
    const int r0 = (t / CG) * 4;
    const float* Ab = Al + r0 * K;
    float4 acc0 = {0, 0, 0, 0}, acc1 = {0, 0, 0, 0}, acc2 = {0, 0, 0, 0}, acc3 = {0, 0, 0, 0};

#pragma unroll 2
    for (int k4 = 0; k4 < K / 4; ++k4) {
        float4 a0 = *(const float4*)(Ab + 0 * K + k4 * 4);
        float4 a1 = *(const float4*)(Ab + 1 * K + k4 * 4);
        float4 a2 = *(const float4*)(Ab + 2 * K + k4 * 4);
        float4 a3 = *(const float4*)(Ab + 3 * K + k4 * 4);
        float4 w0 = *(const float4*)(Wl + (k4 * 4 + 0) * C + c0);
        float4 w1 = *(const float4*)(Wl + (k4 * 4 + 1) * C + c0);
        float4 w2 = *(const float4*)(Wl + (k4 * 4 + 2) * C + c0);
        float4 w3 = *(const float4*)(Wl + (k4 * 4 + 3) * C + c0);
        FMA4(acc0, a0.x, w0) FMA4(acc1, a1.x, w0) FMA4(acc2, a2.x, w0) FMA4(acc3, a3.x, w0)
        FMA4(acc0, a0.y, w1) FMA4(acc1, a1.y, w1) FMA4(acc2, a2.y, w1) FMA4(acc3, a3.y, w1)
        FMA4(acc0, a0.z, w2) FMA4(acc1, a1.z, w2) FMA4(acc2, a2.z, w2) FMA4(acc3, a3.z, w2)
        FMA4(acc0, a0.w, w3) FMA4(acc1, a1.w, w3) FMA4(acc2, a2.w, w3) FMA4(acc3, a3.w, w3)
    }

    const int row = row0 + r0;
#pragma unroll
    for (int i = 0; i < 4; ++i) {
        int rr = row + i;
        if (rr < N) {
            float d = dinv[rr];
            float4 fr = (i == 0) ? acc0 : (i == 1) ? acc1 : (i == 2) ? acc2 : acc3;
            ushort4 o;
            o.x = f2bf(fr.x * d); o.y = f2bf(fr.y * d);
            o.z = f2bf(fr.z * d); o.w = f2bf(fr.w * d);
            *(ushort4*)(out + (size_t)rr * C + c0) = o;
        }
    }
}

// ---------------- gather C=64 (R17 proven): one node/wave, 16 edges, pre-scaled ------
#define G64_LOAD(SS) bf2f(hs[(size_t)(SS) * 64 + lane])
__global__ void __launch_bounds__(256) gather64_kernel(
        const unsigned short* __restrict__ hs, const float* __restrict__ dinv,
        const int* __restrict__ offs, const int* __restrict__ csr_src,
        const float* __restrict__ b, unsigned short* __restrict__ out, int N) {
    const int lane = threadIdx.x & 63;
    const int d = blockIdx.x * 4 + (threadIdx.x >> 6);  // wave-uniform
    if (d >= N) return;
    const int beg = offs[d];
    const int end = offs[d + 1];
    float acc0 = G64_LOAD(d);  // self-loop (pre-scaled table)
    float acc1 = 0.f, acc2 = 0.f, acc3 = 0.f;
    int j = beg;
    for (; j + 15 < end; j += 16) {
        int s0 = csr_src[j + 0], s1 = csr_src[j + 1], s2 = csr_src[j + 2], s3 = csr_src[j + 3];
        int s4 = csr_src[j + 4], s5 = csr_src[j + 5], s6 = csr_src[j + 6], s7 = csr_src[j + 7];
        int s8 = csr_src[j + 8], s9 = csr_src[j + 9], sa = csr_src[j + 10], sb = csr_src[j + 11];
        int sc = csr_src[j + 12], sd = csr_src[j + 13], se = csr_src[j + 14], sf = csr_src[j + 15];
        float v0 = G64_LOAD(s0), v1 = G64_LOAD(s1), v2 = G64_LOAD(s2), v3 = G64_LOAD(s3);
        float v4 = G64_LOAD(s4), v5 = G64_LOAD(s5), v6 = G64_LOAD(s6), v7 = G64_LOAD(s7);
        float v8 = G64_LOAD(s8), v9 = G64_LOAD(s9), va = G64_LOAD(sa), vb = G64_LOAD(sb);
        float vc = G64_LOAD(sc), vd = G64_LOAD(sd), ve = G64_LOAD(se), vf = G64_LOAD(sf);
        acc0 += v0; acc1 += v1; acc2 += v2; acc3 += v3;
        acc0 += v4; acc1 += v5; acc2 += v6; acc3 += v7;
        acc0 += v8; acc1 += v9; acc2 += va; acc3 += vb;
        acc0 += vc; acc1 += vd; acc2 += ve; acc3 += vf;
    }
    if (j + 7 < end) {
        int s0 = csr_src[j + 0], s1 = csr_src[j + 1], s2 = csr_src[j + 2], s3 = csr_src[j + 3];
        int s4 = csr_src[j + 4], s5 = csr_src[j + 5], s6 = csr_src[j + 6], s7 = csr_src[j + 7];
        float v0 = G64_LOAD(s0), v1 = G64_LOAD(s1), v2 = G64_LOAD(s2), v3 = G64_LOAD(s3);
        float v4 = G64_LOAD(s4), v5 = G64_LOAD(s5), v6 = G64_LOAD(s6), v7 = G64_LOAD(s7);
        acc0 += v0; acc1 += v1; acc2 += v2; acc3 += v3;
        acc0 += v4; acc1 += v5; acc2 += v6; acc3 += v7;
        j += 8;
    }
    if (j + 3 < end) {
        int s0 = csr_src[j + 0], s1 = csr_src[j + 1], s2 = csr_src[j + 2], s3 = csr_src[j + 3];
        acc0 += G64_LOAD(s0); acc1 += G64_LOAD(s1); acc2 += G64_LOAD(s2); acc3 += G64_LOAD(s3);
        j += 4;
    }
    for (; j < end; ++j) acc0 += G64_LOAD(csr_src[j]);
    float r = ((acc0 + acc1) + (acc2 + acc3)) * dinv[d] + b[lane];
    r = fmaxf(r, 0.f);  // relu (layer 1)
    out[(size_t)d * 64 + lane] = f2bf(r);
}

// ---------------- gather C=32 (R14 proven): 2 nodes/wave, 16 edges, pre-scaled -------
#define G32_LOAD(SS) bf2f(hs[(size_t)(SS) * 32 + lane])
__global__ void __launch_bounds__(256) gather32_kernel(
        const unsigned short* __restrict__ hs, const float* __restrict__ dinv,
        const int* __restrict__ offs, const int* __restrict__ csr_src,
        const float* __restrict__ b, float* __restrict__ out, int N) {
    const int lane = threadIdx.x & 31;
    const int d = blockIdx.x * 8 + (threadIdx.x >> 5);
    if (d >= N) return;
    const int beg = offs[d];
    const int end = offs[d + 1];
    float acc0 = G32_LOAD(d);  // self-loop
    float acc1 = 0.f, acc2 = 0.f, acc3 = 0.f;
    int j = beg;
    for (; j + 15 < end; j += 16) {
        int s0 = csr_src[j + 0], s1 = csr_src[j + 1], s2 = csr_src[j + 2], s3 = csr_src[j + 3];
        int s4 = csr_src[j + 4], s5 = csr_src[j + 5], s6 = csr_src[j + 6], s7 = csr_src[j + 7];
        int s8 = csr_src[j + 8], s9 = csr_src[j + 9], sa = csr_src[j + 10], sb = csr_src[j + 11];
        int sc = csr_src[j + 12], sd = csr_src[j + 13], se = csr_src[j + 14], sf = csr_src[j + 15];
        float v0 = G32_LOAD(s0), v1 = G32_LOAD(s1), v2 = G32_LOAD(s2), v3 = G32_LOAD(s3);
        float v4 = G32_LOAD(s4), v5 = G32_LOAD(s5), v6 = G32_LOAD(s6), v7 = G32_LOAD(s7);
        float v8 = G32_LOAD(s8), v9 = G32_LOAD(s9), va = G32_LOAD(sa), vb = G32_LOAD(sb);
        float vc = G32_LOAD(sc), vd = G32_LOAD(sd), ve = G32_LOAD(se), vf = G32_LOAD(sf);
        acc0 += v0; acc1 += v1; acc2 += v2; acc3 += v3;
        acc0 += v4; acc1 += v5; acc2 += v6; acc3 += v7;
        acc0 += v8; acc1 += v9; acc2 += va; acc3 += vb;
        acc0 += vc; acc1 += vd; acc2 += ve; acc3 += vf;
    }
    if (j + 7 < end) {
        int s0 = csr_src[j + 0], s1 = csr_src[j + 1], s2 = csr_src[j + 2], s3 = csr_src[j + 3];
        int s4 = csr_src[j + 4], s5 = csr_src[j + 5], s6 = csr_src[j + 6], s7 = csr_src[j + 7];
        float v0 = G32_LOAD(s0), v1 = G32_LOAD(s1), v2 = G32_LOAD(s2), v3 = G32_LOAD(s3);
        float v4 = G32_LOAD(s4), v5 = G32_LOAD(s5), v6 = G32_LOAD(s6), v7 = G32_LOAD(s7);
        acc0 += v0; acc1 += v1; acc2 += v2; acc3 += v3;
        acc0 += v4; acc1 += v5; acc2 += v6; acc3 += v7;
        j += 8;
    }
    if (j + 3 < end) {
        int s0 = csr_src[j + 0], s1 = csr_src[j + 1], s2 = csr_src[j + 2], s3 = csr_src[j + 3];
        acc0 += G32_LOAD(s0); acc1 += G32_LOAD(s1); acc2 += G32_LOAD(s2); acc3 += G32_LOAD(s3);
        j += 4;
    }
    for (; j < end; ++j) acc0 += G32_LOAD(csr_src[j]);
    float r = ((acc0 + acc1) + (acc2 + acc3)) * dinv[d] + b[lane];
    out[(size_t)d * 32 + lane] = r;
}

extern "C" void kernel_launch(void* const* d_in, const int* in_sizes, int n_in,
                              void* d_out, int out_size, void* d_ws, size_t ws_size,
                              hipStream_t stream) {
    const float* x = (const float*)d_in[0];
    const int* ei = (const int*)d_in[1];
    const float* W1 = (const float*)d_in[2];
    const float* b1 = (const float*)d_in[3];
    const float* W2 = (const float*)d_in[4];
    const float* b2 = (const float*)d_in[5];

    const int N = in_sizes[0] / 128;  // 100000
    const int E = in_sizes[1] / 2;    // 1600000
    const int* src = ei;
    const int* dst = ei + E;
    const int nbk = NBKT(N);          // 782

    // workspace layout (4-byte units unless noted)
    int* bcnt = (int*)d_ws;                            // nbk (pad 1024)
    int* boffs = bcnt + 1024;                          // nbk+1 (pad 1024)
    int* gcursor = boffs + 1024;                       // nbk (pad 1024)
    float* dinv = (float*)(gcursor + 1024);            // N
    int* offs = (int*)(dinv + ((N + 255) & ~255));     // N+1
    int* entries = offs + ((N + 1 + 255) & ~255);      // E
    int* csr_src = entries + ((E + 255) & ~255);       // E
    unsigned short* h1u = (unsigned short*)(csr_src + ((E + 255) & ~255));  // N*64 bf16
    unsigned short* h2b = h1u + (size_t)N * 64;        // N*64 bf16
    unsigned short* h3s = h1u;                         // reuse h1u region (N*32 bf16)
    float* out = (float*)d_out;

    const int nBin = (E + BF_CHUNK - 1) / BF_CHUNK;    // 391
    const int GB = (N + 63) / 64;                      // 1563 gemm1 tiles
    const int GA = GB / 2;                             // 781 in fusedA
    const int GBB = GB - GA;                           // 782 in fusedB
    const int rowBase = GA * 64;

    // 1) bucket histogram -> offsets
    hipMemsetAsync(bcnt, 0, 1024 * 4, stream);
    bhist_kernel<<<(E + BH_CHUNK - 1) / BH_CHUNK, 256, 0, stream>>>(dst, E, nbk, bcnt);
    bscan_kernel<<<1, 1024, 0, stream>>>(bcnt, nbk, E, boffs, gcursor);

    // 2) fusedA: binfill + gemm1 rows [0, rowBase)   (h1u unscaled)
    fusedA_kernel<<<nBin + GA, 256, 0, stream>>>(src, dst, E, nbk, gcursor, entries, nBin,
                                                 x, W1, h1u, N);

    // 3) fusedB: bucket2csr (emits offs, csr_src, dinv) + gemm1 rows [rowBase, N)
    fusedB_kernel<<<nbk + GBB, 256, 0, stream>>>(entries, boffs, nbk, offs, csr_src, dinv,
                                                 N, E, x, W1, h1u, rowBase);

    // 4) scale: h1u *= dinv[row]  -> pre-scaled table for gather64
    scale_h1_kernel<<<(N * 8 + 255) / 256, 256, 0, stream>>>(h1u, dinv, N);

    // 5) h2b = bf16(relu(dinv*(gather h1s) + b1))
    gather64_kernel<<<(N + 3) / 4, 256, 0, stream>>>(h1u, dinv, offs, csr_src, b1, h2b, N);

    // 6) h3s = bf16((h2b @ W2) * dinv)
    gemm2_kernel<64, 32, 128><<<(N + 127) / 128, 256, 0, stream>>>(h2b, W2, dinv, h3s, N);

    // 7) out = dinv*(gather h3s) + b2   (fp32)
    gather32_kernel<<<(N + 7) / 8, 256, 0, stream>>>(h3s, dinv, offs, csr_src, b2, out, N);
}

// Round 20
// 197.131 us; speedup vs baseline: 1.0725x; 1.0218x over previous
//
#include <hip/hip_runtime.h>

// GCN 2-layer. R20: fix R19's fused-kernel occupancy -- gemm1_body now stages only
// W1 in LDS (32KB, was 64KB with the A-tile) and streams A from global (each element
// read once/block, 4-row broadcast pattern). 64KB LDS capped fusedA at 2 blocks/CU
// (occ 16.6%), strangling the latency-bound binfill half.

#define NBKT(n) (((n) + 127) >> 7)

__device__ inline float bf2f(unsigned short u) {
    union { unsigned int i; float f; } v;
    v.i = ((unsigned int)u) << 16;
    return v.f;
}
__device__ inline unsigned short f2bf(float f) {
    union { float f; unsigned int i; } v;
    v.f = f;
    unsigned int u = v.i;
    return (unsigned short)((u + 0x7fff + ((u >> 16) & 1)) >> 16);  // RTN-even
}

// ---------------- bucket histogram (R13 proven) ----------------
#define BH_CHUNK 4096
__global__ void __launch_bounds__(256) bhist_kernel(
        const int* __restrict__ dst, int E, int nbk, int* __restrict__ bcnt) {
    __shared__ int cnt[NBKT(100000)];
    const int t = threadIdx.x;
    const int beg = blockIdx.x * BH_CHUNK;
    const int end = min(E, beg + BH_CHUNK);
    for (int b = t; b < nbk; b += 256) cnt[b] = 0;
    __syncthreads();
    for (int i = beg + t; i < end; i += 256) atomicAdd(&cnt[dst[i] >> 7], 1);
    __syncthreads();
    for (int b = t; b < nbk; b += 256) {
        int c = cnt[b];
        if (c) atomicAdd(&bcnt[b], c);
    }
}

// ---------------- bucket offsets (R13 proven) ----------------
__global__ void bscan_kernel(const int* __restrict__ bcnt, int nbk, int E,
                             int* __restrict__ boffs, int* __restrict__ gcursor) {
    __shared__ int s[1024];
    const int t = threadIdx.x;
    int v = (t < nbk) ? bcnt[t] : 0;
    s[t] = v;
    __syncthreads();
    for (int off = 1; off < 1024; off <<= 1) {
        int x = (t >= off) ? s[t - off] : 0;
        __syncthreads();
        s[t] += x;
        __syncthreads();
    }
    if (t < nbk) {
        int excl = s[t] - v;
        boffs[t] = excl;
        gcursor[t] = excl;
    }
    if (t == 0) boffs[nbk] = E;
}

// ---------------- gemm1 body v2: W in LDS (32KB), A streamed from global ----------
#define FMA4(ACC, AV, WV) \
    ACC.x += (AV) * (WV).x; ACC.y += (AV) * (WV).y; ACC.z += (AV) * (WV).z; ACC.w += (AV) * (WV).w;

__device__ __forceinline__ void gemm1_body(
        const float* __restrict__ A, const float* __restrict__ W,
        unsigned short* __restrict__ out, int N, int row0, float* Wl) {
    constexpr int K = 128, C = 64, F4R = 32, CG = 16;
    const int t = threadIdx.x;
    for (int i = t; i < K * C / 4; i += 256) ((float4*)Wl)[i] = ((const float4*)W)[i];
    __syncthreads();

    const int c0 = (t % CG) * 4;
    const int r0 = (t / CG) * 4;
    // clamped row indices for loads (stores are guarded)
    const int r_0 = min(row0 + r0 + 0, N - 1);
    const int r_1 = min(row0 + r0 + 1, N - 1);
    const int r_2 = min(row0 + r0 + 2, N - 1);
    const int r_3 = min(row0 + r0 + 3, N - 1);
    const float4* A4 = (const float4*)A;

    float4 acc0 = {0, 0, 0, 0}, acc1 = {0, 0, 0, 0}, acc2 = {0, 0, 0, 0}, acc3 = {0, 0, 0, 0};

#pragma unroll 2
    for (int k4 = 0; k4 < F4R; ++k4) {
        float4 a0 = A4[(size_t)r_0 * F4R + k4];
        float4 a1 = A4[(size_t)r_1 * F4R + k4];
        float4 a2 = A4[(size_t)r_2 * F4R + k4];
        float4 a3 = A4[(size_t)r_3 * F4R + k4];
        float4 w0 = *(const float4*)(Wl + (k4 * 4 + 0) * C + c0);
        float4 w1 = *(const float4*)(Wl + (k4 * 4 + 1) * C + c0);
        float4 w2 = *(const float4*)(Wl + (k4 * 4 + 2) * C + c0);
        float4 w3 = *(const float4*)(Wl + (k4 * 4 + 3) * C + c0);
        FMA4(acc0, a0.x, w0) FMA4(acc1, a1.x, w0) FMA4(acc2, a2.x, w0) FMA4(acc3, a3.x, w0)
        FMA4(acc0, a0.y, w1) FMA4(acc1, a1.y, w1) FMA4(acc2, a2.y, w1) FMA4(acc3, a3.y, w1)
        FMA4(acc0, a0.z, w2) FMA4(acc1, a1.z, w2) FMA4(acc2, a2.z, w2) FMA4(acc3, a3.z, w2)
        FMA4(acc0, a0.w, w3) FMA4(acc1, a1.w, w3) FMA4(acc2, a2.w, w3) FMA4(acc3, a3.w, w3)
    }

    const int row = row0 + r0;
#pragma unroll
    for (int i = 0; i < 4; ++i) {
        int rr = row + i;
        if (rr < N) {
            float4 fr = (i == 0) ? acc0 : (i == 1) ? acc1 : (i == 2) ? acc2 : acc3;
            ushort4 o;
            o.x = f2bf(fr.x); o.y = f2bf(fr.y); o.z = f2bf(fr.z); o.w = f2bf(fr.w);
            *(ushort4*)(out + (size_t)rr * C + c0) = o;
        }
    }
}

// ---------------- fused A: binfill (blocks < nBin) + gemm1a  (32KB LDS) ----------
#define BF_CHUNK 4096
__global__ void __launch_bounds__(256) fusedA_kernel(
        const int* __restrict__ src, const int* __restrict__ dst, int E, int nbk,
        int* __restrict__ gcursor, int* __restrict__ entries, int nBin,
        const float* __restrict__ x, const float* __restrict__ W1,
        unsigned short* __restrict__ h1u, int N) {
    __shared__ float smem[8192];  // 32KB: gemm Wl, or binfill cnt/gbase/rank (9.4KB)
    if ((int)blockIdx.x < nBin) {
        int* cnt = (int*)smem;
        int* gbase = cnt + NBKT(100000);
        int* rank = gbase + NBKT(100000);
        const int t = threadIdx.x;
        const int beg = blockIdx.x * BF_CHUNK;
        const int end = min(E, beg + BF_CHUNK);
        for (int b = t; b < nbk; b += 256) cnt[b] = 0;
        __syncthreads();
        for (int i = beg + t; i < end; i += 256) atomicAdd(&cnt[dst[i] >> 7], 1);
        __syncthreads();
        for (int b = t; b < nbk; b += 256) {
            int c = cnt[b];
            gbase[b] = c ? atomicAdd(&gcursor[b], c) : 0;
            rank[b] = 0;
        }
        __syncthreads();
        for (int i = beg + t; i < end; i += 256) {
            int d = dst[i];
            int b = d >> 7;
            int r = atomicAdd(&rank[b], 1);
            entries[gbase[b] + r] = (src[i] << 7) | (d & 127);
        }
    } else {
        int row0 = (blockIdx.x - nBin) * 64;
        gemm1_body(x, W1, h1u, N, row0, smem);
    }
}

// ---------------- fused B: bucket2csr (blocks < nbk) + gemm1b  (32KB LDS) ----------
__global__ void __launch_bounds__(256) fusedB_kernel(
        const int* __restrict__ entries, const int* __restrict__ boffs, int nbk,
        int* __restrict__ offs, int* __restrict__ csr_src, float* __restrict__ dinv,
        int N, int E,
        const float* __restrict__ x, const float* __restrict__ W1,
        unsigned short* __restrict__ h1u, int rowBase) {
    __shared__ float smem[8192];  // 32KB
    if ((int)blockIdx.x < nbk) {
        int* cnt = (int*)smem;
        int* s = cnt + 128;
        int* rank = s + 128;
        const int t = threadIdx.x;
        const int b = blockIdx.x;
        const int beg = boffs[b];
        const int end = boffs[b + 1];
        if (t < 128) { cnt[t] = 0; rank[t] = 0; }
        __syncthreads();
        for (int i = beg + t; i < end; i += 256) atomicAdd(&cnt[entries[i] & 127], 1);
        __syncthreads();
        if (t < 128) s[t] = cnt[t];
        __syncthreads();
        for (int off = 1; off < 128; off <<= 1) {
            int x2 = 0;
            if (t < 128 && t >= off) x2 = s[t - off];
            __syncthreads();
            if (t < 128) s[t] += x2;
            __syncthreads();
        }
        const int node0 = b * 128;
        if (t < 128 && node0 + t < N) {
            offs[node0 + t] = beg + s[t] - cnt[t];
            dinv[node0 + t] = rsqrtf((float)cnt[t] + 1.0f);  // +1 = self-loop
        }
        if (b == 0 && t == 0) offs[N] = E;
        __syncthreads();
        for (int i = beg + t; i < end; i += 256) {
            int e = entries[i];
            int d = e & 127;
            int r = atomicAdd(&rank[d], 1);
            csr_src[beg + s[d] - cnt[d] + r] = (int)((unsigned)e >> 7);
        }
    } else {
        int row0 = rowBase + (blockIdx.x - nbk) * 64;
        gemm1_body(x, W1, h1u, N, row0, smem);
    }
}

// ---------------- scale_h1: h1u[row][*] *= dinv[row]  (bf16 in-place, coalesced) -----
__global__ void __launch_bounds__(256) scale_h1_kernel(
        unsigned short* __restrict__ h, const float* __restrict__ dinv, int N) {
    int idx = blockIdx.x * 256 + threadIdx.x;  // one thread per 8 bf16 (16B)
    if (idx >= N * 8) return;
    float d = dinv[idx >> 3];
    uint4* p = (uint4*)h + idx;
    uint4 v = *p;
#define SCH(U) { \
        float lo = bf2f((unsigned short)((U) & 0xffffu)) * d; \
        float hi = bf2f((unsigned short)((U) >> 16)) * d; \
        (U) = (unsigned)f2bf(lo) | ((unsigned)f2bf(hi) << 16); }
    SCH(v.x) SCH(v.y) SCH(v.z) SCH(v.w)
#undef SCH
    *p = v;
}

// ---------------- gemm2 (R6/R17 proven): bf16 in, bf16 out, dinv scale ----------------
template <int K, int C, int BR>
__global__ void __launch_bounds__(256) gemm2_kernel(
        const unsigned short* __restrict__ A, const float* __restrict__ W,
        const float* __restrict__ dinv, unsigned short* __restrict__ out, int N) {
    constexpr int F4R = K / 4;
    constexpr int CG = C / 4;
    static_assert(256 / CG * 4 == BR, "geometry");
    __shared__ float Wl[K * C];
    __shared__ float Al[BR * K];

    const int t = threadIdx.x;
    for (int i = t; i < K * C / 4; i += 256) ((float4*)Wl)[i] = ((const float4*)W)[i];
    const int row0 = blockIdx.x * BR;
    for (int i = t; i < BR * F4R; i += 256) {
        int r = i / F4R, k4 = i % F4R;
        float4 v = make_float4(0.f, 0.f, 0.f, 0.f);
        if (row0 + r < N) {
            ushort4 u = ((const ushort4*)A)[(size_t)(row0 + r) * F4R + k4];
            v.x = bf2f(u.x); v.y = bf2f(u.y); v.z = bf2f(u.z); v.w = bf2f(u.w);
        }
        *(float4*)(Al + r * K + k4 * 4) = v;
    }
    __syncthreads();

    const int c0 = (t % CG) * 4;
    const int r0 = (t / CG) * 4;
    const float* Ab = Al + r0 * K;
    float4 acc0 = {0, 0, 0, 0}, acc1 = {0, 0, 0, 0}, acc2 = {0, 0, 0, 0}, acc3 = {0, 0, 0, 0};

#pragma unroll 2
    for (int k4 = 0; k4 < K / 4; ++k4) {
        float4 a0 = *(const float4*)(Ab + 0 * K + k4 * 4);
        float4 a1 = *(const float4*)(Ab + 1 * K + k4 * 4);
        float4 a2 = *(const float4*)(Ab + 2 * K + k4 * 4);
        float4 a3 = *(const float4*)(Ab + 3 * K + k4 * 4);
        float4 w0 = *(const float4*)(Wl + (k4 * 4 + 0) * C + c0);
        float4 w1 = *(const float4*)(Wl + (k4 * 4 + 1) * C + c0);
        float4 w2 = *(const float4*)(Wl + (k4 * 4 + 2) * C + c0);
        float4 w3 = *(const float4*)(Wl + (k4 * 4 + 3) * C + c0);
        FMA4(acc0, a0.x, w0) FMA4(acc1, a1.x, w0) FMA4(acc2, a2.x, w0) FMA4(acc3, a3.x, w0)
        FMA4(acc0, a0.y, w1) FMA4(acc1, a1.y, w1) FMA4(acc2, a2.y, w1) FMA4(acc3, a3.y, w1)
        FMA4(acc0, a0.z, w2) FMA4(acc1, a1.z, w2) FMA4(acc2, a2.z, w2) FMA4(acc3, a3.z, w2)
        FMA4(acc0, a0.w, w3) FMA4(acc1, a1.w, w3) FMA4(acc2, a2.w, w3) FMA4(acc3, a3.w, w3)
    }

    const int row = row0 + r0;
#pragma unroll
    for (int i = 0; i < 4; ++i) {
        int rr = row + i;
        if (rr < N) {
            float d = dinv[rr];
            float4 fr = (i == 0) ? acc0 : (i == 1) ? acc1 : (i == 2) ? acc2 : acc3;
            ushort4 o;
            o.x = f2bf(fr.x * d); o.y = f2bf(fr.y * d);
            o.z = f2bf(fr.z * d); o.w = f2bf(fr.w * d);
            *(ushort4*)(out + (size_t)rr * C + c0) = o;
        }
    }
}

// ---------------- gather C=64 (R17 proven): one node/wave, 16 edges, pre-scaled ------
#define G64_LOAD(SS) bf2f(hs[(size_t)(SS) * 64 + lane])
__global__ void __launch_bounds__(256) gather64_kernel(
        const unsigned short* __restrict__ hs, const float* __restrict__ dinv,
        const int* __restrict__ offs, const int* __restrict__ csr_src,
        const float* __restrict__ b, unsigned short* __restrict__ out, int N) {
    const int lane = threadIdx.x & 63;
    const int d = blockIdx.x * 4 + (threadIdx.x >> 6);  // wave-uniform
    if (d >= N) return;
    const int beg = offs[d];
    const int end = offs[d + 1];
    float acc0 = G64_LOAD(d);  // self-loop (pre-scaled table)
    float acc1 = 0.f, acc2 = 0.f, acc3 = 0.f;
    int j = beg;
    for (; j + 15 < end; j += 16) {
        int s0 = csr_src[j + 0], s1 = csr_src[j + 1], s2 = csr_src[j + 2], s3 = csr_src[j + 3];
        int s4 = csr_src[j + 4], s5 = csr_src[j + 5], s6 = csr_src[j + 6], s7 = csr_src[j + 7];
        int s8 = csr_src[j + 8], s9 = csr_src[j + 9], sa = csr_src[j + 10], sb = csr_src[j + 11];
        int sc = csr_src[j + 12], sd = csr_src[j + 13], se = csr_src[j + 14], sf = csr_src[j + 15];
        float v0 = G64_LOAD(s0), v1 = G64_LOAD(s1), v2 = G64_LOAD(s2), v3 = G64_LOAD(s3);
        float v4 = G64_LOAD(s4), v5 = G64_LOAD(s5), v6 = G64_LOAD(s6), v7 = G64_LOAD(s7);
        float v8 = G64_LOAD(s8), v9 = G64_LOAD(s9), va = G64_LOAD(sa), vb = G64_LOAD(sb);
        float vc = G64_LOAD(sc), vd = G64_LOAD(sd), ve = G64_LOAD(se), vf = G64_LOAD(sf);
        acc0 += v0; acc1 += v1; acc2 += v2; acc3 += v3;
        acc0 += v4; acc1 += v5; acc2 += v6; acc3 += v7;
        acc0 += v8; acc1 += v9; acc2 += va; acc3 += vb;
        acc0 += vc; acc1 += vd; acc2 += ve; acc3 += vf;
    }
    if (j + 7 < end) {
        int s0 = csr_src[j + 0], s1 = csr_src[j + 1], s2 = csr_src[j + 2], s3 = csr_src[j + 3];
        int s4 = csr_src[j + 4], s5 = csr_src[j + 5], s6 = csr_src[j + 6], s7 = csr_src[j + 7];
        float v0 = G64_LOAD(s0), v1 = G64_LOAD(s1), v2 = G64_LOAD(s2), v3 = G64_LOAD(s3);
        float v4 = G64_LOAD(s4), v5 = G64_LOAD(s5), v6 = G64_LOAD(s6), v7 = G64_LOAD(s7);
        acc0 += v0; acc1 += v1; acc2 += v2; acc3 += v3;
        acc0 += v4; acc1 += v5; acc2 += v6; acc3 += v7;
        j += 8;
    }
    if (j + 3 < end) {
        int s0 = csr_src[j + 0], s1 = csr_src[j + 1], s2 = csr_src[j + 2], s3 = csr_src[j + 3];
        acc0 += G64_LOAD(s0); acc1 += G64_LOAD(s1); acc2 += G64_LOAD(s2); acc3 += G64_LOAD(s3);
        j += 4;
    }
    for (; j < end; ++j) acc0 += G64_LOAD(csr_src[j]);
    float r = ((acc0 + acc1) + (acc2 + acc3)) * dinv[d] + b[lane];
    r = fmaxf(r, 0.f);  // relu (layer 1)
    out[(size_t)d * 64 + lane] = f2bf(r);
}

// ---------------- gather C=32 (R14 proven): 2 nodes/wave, 16 edges, pre-scaled -------
#define G32_LOAD(SS) bf2f(hs[(size_t)(SS) * 32 + lane])
__global__ void __launch_bounds__(256) gather32_kernel(
        const unsigned short* __restrict__ hs, const float* __restrict__ dinv,
        const int* __restrict__ offs, const int* __restrict__ csr_src,
        const float* __restrict__ b, float* __restrict__ out, int N) {
    const int lane = threadIdx.x & 31;
    const int d = blockIdx.x * 8 + (threadIdx.x >> 5);
    if (d >= N) return;
    const int beg = offs[d];
    const int end = offs[d + 1];
    float acc0 = G32_LOAD(d);  // self-loop
    float acc1 = 0.f, acc2 = 0.f, acc3 = 0.f;
    int j = beg;
    for (; j + 15 < end; j += 16) {
        int s0 = csr_src[j + 0], s1 = csr_src[j + 1], s2 = csr_src[j + 2], s3 = csr_src[j + 3];
        int s4 = csr_src[j + 4], s5 = csr_src[j + 5], s6 = csr_src[j + 6], s7 = csr_src[j + 7];
        int s8 = csr_src[j + 8], s9 = csr_src[j + 9], sa = csr_src[j + 10], sb = csr_src[j + 11];
        int sc = csr_src[j + 12], sd = csr_src[j + 13], se = csr_src[j + 14], sf = csr_src[j + 15];
        float v0 = G32_LOAD(s0), v1 = G32_LOAD(s1), v2 = G32_LOAD(s2), v3 = G32_LOAD(s3);
        float v4 = G32_LOAD(s4), v5 = G32_LOAD(s5), v6 = G32_LOAD(s6), v7 = G32_LOAD(s7);
        float v8 = G32_LOAD(s8), v9 = G32_LOAD(s9), va = G32_LOAD(sa), vb = G32_LOAD(sb);
        float vc = G32_LOAD(sc), vd = G32_LOAD(sd), ve = G32_LOAD(se), vf = G32_LOAD(sf);
        acc0 += v0; acc1 += v1; acc2 += v2; acc3 += v3;
        acc0 += v4; acc1 += v5; acc2 += v6; acc3 += v7;
        acc0 += v8; acc1 += v9; acc2 += va; acc3 += vb;
        acc0 += vc; acc1 += vd; acc2 += ve; acc3 += vf;
    }
    if (j + 7 < end) {
        int s0 = csr_src[j + 0], s1 = csr_src[j + 1], s2 = csr_src[j + 2], s3 = csr_src[j + 3];
        int s4 = csr_src[j + 4], s5 = csr_src[j + 5], s6 = csr_src[j + 6], s7 = csr_src[j + 7];
        float v0 = G32_LOAD(s0), v1 = G32_LOAD(s1), v2 = G32_LOAD(s2), v3 = G32_LOAD(s3);
        float v4 = G32_LOAD(s4), v5 = G32_LOAD(s5), v6 = G32_LOAD(s6), v7 = G32_LOAD(s7);
        acc0 += v0; acc1 += v1; acc2 += v2; acc3 += v3;
        acc0 += v4; acc1 += v5; acc2 += v6; acc3 += v7;
        j += 8;
    }
    if (j + 3 < end) {
        int s0 = csr_src[j + 0], s1 = csr_src[j + 1], s2 = csr_src[j + 2], s3 = csr_src[j + 3];
        acc0 += G32_LOAD(s0); acc1 += G32_LOAD(s1); acc2 += G32_LOAD(s2); acc3 += G32_LOAD(s3);
        j += 4;
    }
    for (; j < end; ++j) acc0 += G32_LOAD(csr_src[j]);
    float r = ((acc0 + acc1) + (acc2 + acc3)) * dinv[d] + b[lane];
    out[(size_t)d * 32 + lane] = r;
}

extern "C" void kernel_launch(void* const* d_in, const int* in_sizes, int n_in,
                              void* d_out, int out_size, void* d_ws, size_t ws_size,
                              hipStream_t stream) {
    const float* x = (const float*)d_in[0];
    const int* ei = (const int*)d_in[1];
    const float* W1 = (const float*)d_in[2];
    const float* b1 = (const float*)d_in[3];
    const float* W2 = (const float*)d_in[4];
    const float* b2 = (const float*)d_in[5];

    const int N = in_sizes[0] / 128;  // 100000
    const int E = in_sizes[1] / 2;    // 1600000
    const int* src = ei;
    const int* dst = ei + E;
    const int nbk = NBKT(N);          // 782

    // workspace layout (4-byte units unless noted)
    int* bcnt = (int*)d_ws;                            // nbk (pad 1024)
    int* boffs = bcnt + 1024;                          // nbk+1 (pad 1024)
    int* gcursor = boffs + 1024;                       // nbk (pad 1024)
    float* dinv = (float*)(gcursor + 1024);            // N
    int* offs = (int*)(dinv + ((N + 255) & ~255));     // N+1
    int* entries = offs + ((N + 1 + 255) & ~255);      // E
    int* csr_src = entries + ((E + 255) & ~255);       // E
    unsigned short* h1u = (unsigned short*)(csr_src + ((E + 255) & ~255));  // N*64 bf16
    unsigned short* h2b = h1u + (size_t)N * 64;        // N*64 bf16
    unsigned short* h3s = h1u;                         // reuse h1u region (N*32 bf16)
    float* out = (float*)d_out;

    const int nBin = (E + BF_CHUNK - 1) / BF_CHUNK;    // 391
    const int GB = (N + 63) / 64;                      // 1563 gemm1 tiles
    const int GA = GB / 2;                             // 781 in fusedA
    const int GBB = GB - GA;                           // 782 in fusedB
    const int rowBase = GA * 64;

    // 1) bucket histogram -> offsets
    hipMemsetAsync(bcnt, 0, 1024 * 4, stream);
    bhist_kernel<<<(E + BH_CHUNK - 1) / BH_CHUNK, 256, 0, stream>>>(dst, E, nbk, bcnt);
    bscan_kernel<<<1, 1024, 0, stream>>>(bcnt, nbk, E, boffs, gcursor);

    // 2) fusedA: binfill + gemm1 rows [0, rowBase)   (h1u unscaled)
    fusedA_kernel<<<nBin + GA, 256, 0, stream>>>(src, dst, E, nbk, gcursor, entries, nBin,
                                                 x, W1, h1u, N);

    // 3) fusedB: bucket2csr (emits offs, csr_src, dinv) + gemm1 rows [rowBase, N)
    fusedB_kernel<<<nbk + GBB, 256, 0, stream>>>(entries, boffs, nbk, offs, csr_src, dinv,
                                                 N, E, x, W1, h1u, rowBase);

    // 4) scale: h1u *= dinv[row]  -> pre-scaled table for gather64
    scale_h1_kernel<<<(N * 8 + 255) / 256, 256, 0, stream>>>(h1u, dinv, N);

    // 5) h2b = bf16(relu(dinv*(gather h1s) + b1))
    gather64_kernel<<<(N + 3) / 4, 256, 0, stream>>>(h1u, dinv, offs, csr_src, b1, h2b, N);

    // 6) h3s = bf16((h2b @ W2) * dinv)
    gemm2_kernel<64, 32, 128><<<(N + 127) / 128, 256, 0, stream>>>(h2b, W2, dinv, h3s, N);

    // 7) out = dinv*(gather h3s) + b2   (fp32)
    gather32_kernel<<<(N + 7) / 8, 256, 0, stream>>>(h3s, dinv, offs, csr_src, b2, out, N);
}